// Round 4
// baseline (128.841 us; speedup 1.0000x reference)
//
#include <hip/hip_runtime.h>
#include <math.h>

namespace {
constexpr int NB = 2048;      // batch
constexpr int NNODE = 6;      // nodes
constexpr int DD = 2048;      // feature dim
constexpr int HH = 1024;      // hidden
constexpr int CC = 200;       // classes
constexpr int K2 = 2 * DD;    // 4096 (concat dim)
constexpr int NPAD = 256;     // padded class dim
constexpr int ZSPLIT = 4;     // split over DD for fused gemm
constexpr float ALPHA_C = 0.015f;
constexpr float SCALE_C = 24.0f;
}

typedef __attribute__((ext_vector_type(8))) short bf16x8;
typedef __attribute__((ext_vector_type(4))) float f32x4;

static __device__ __forceinline__ unsigned short f2bf(float x) {
    union { float f; unsigned int u; } v; v.f = x;
    unsigned int r = v.u + 0x7FFFu + ((v.u >> 16) & 1u);  // RNE
    return (unsigned short)(r >> 16);
}

// node weights s[u] for batch b
static __device__ __forceinline__ void compute_s(const float* __restrict__ cdds,
                                                 int b, float* sv) {
    const float* cd = cdds + (size_t)b * NNODE * 6;
    float cx[NNODE], cy[NNODE];
#pragma unroll
    for (int u = 0; u < NNODE; ++u) {
        cy[u] = (cd[u * 6 + 1] + cd[u * 6 + 3]) * 0.5f;
        cx[u] = (cd[u * 6 + 2] + cd[u * 6 + 4]) * 0.5f;
    }
    float w0[NNODE][NNODE];
    float sum = 0.f;
#pragma unroll
    for (int u = 0; u < NNODE; ++u)
#pragma unroll
        for (int v = 0; v < NNODE; ++v) {
            if (v == u) { w0[u][v] = 0.f; continue; }
            float dx = cx[u] - cx[v];
            float dy = cy[u] - cy[v];
            float w = expf(-ALPHA_C * sqrtf(dx * dx + dy * dy));
            w0[u][v] = w;
            sum += w;
        }
    float mean = sum * (1.f / 30.f);
#pragma unroll
    for (int u = 0; u < NNODE; ++u) {
        float acc = 0.f;
#pragma unroll
        for (int v = 0; v < NNODE; ++v) {
            float tt = w0[u][v] - mean;
            if (v != u && tt > 0.f) acc += tt;
        }
        sv[u] = SCALE_C * acc * 0.2f;   // /(N-1)
    }
}

// ---------------------------------------------------------------------------
// GEMM1 (+bvec): blocks 0..255: Mt[256][4096] = (fc_w @ cls_w)^T bf16.
//   Reads fc_w/cls_w f32, converts in staging (cls_w transposed in-flight).
// blocks 256..280: bvec[c] = fc_b @ cls_w + cls_b.
// ---------------------------------------------------------------------------
__global__ __launch_bounds__(256) void k_gemm1(const float* __restrict__ fc_w,
                                               const float* __restrict__ cls_w,
                                               const float* __restrict__ fc_b,
                                               const float* __restrict__ cls_b,
                                               unsigned short* __restrict__ Mt,
                                               float* __restrict__ bvec)
{
    __shared__ short As[64][68];   // +4 pad: row stride 136B -> 2-way max
    __shared__ short Bs[64][68];
    __shared__ float red[256];
    const int t = threadIdx.x;
    const int bx = blockIdx.x;

    if (bx >= 256) {   // ---- bvec blocks
        const int bb = bx - 256;          // 0..24
        int c8 = t & 7;
        int hs = t >> 3;
        int c = bb * 8 + c8;              // < 200
        float acc = 0.f;
        for (int h = hs; h < HH; h += 32)
            acc += fc_b[h] * cls_w[(size_t)h * CC + c];
        red[t] = acc;
        __syncthreads();
        for (int s = 128; s >= 8; s >>= 1) {
            if (t < s) red[t] += red[t + s];
            __syncthreads();
        }
        if (t < 8) bvec[c] = red[t] + cls_b[c];
        return;
    }

    const int lane = t & 63;
    const int wid = t >> 6;
    const int wm = wid >> 1, wn = wid & 1;
    const int bm = (bx >> 2) * 64;        // over concat dim (4096)
    const int bn = (bx & 3) * 64;         // over class dim (256)

    f32x4 acc[2][2] = {};

    for (int k0 = 0; k0 < HH; k0 += 64) {
        // A tile 64x64: fc_w f32 -> bf16
#pragma unroll
        for (int c = 0; c < 4; ++c) {
            int i = t + c * 256;
            int row = i >> 4;
            int k4 = (i & 15) << 2;
            float4 v = *(const float4*)(fc_w + (size_t)(bm + row) * HH + k0 + k4);
            ushort4 o;
            o.x = f2bf(v.x); o.y = f2bf(v.y); o.z = f2bf(v.z); o.w = f2bf(v.w);
            *(ushort4*)&As[row][k4] = o;
        }
        // B tile: cls_w[k0+kr][bn+n4..+3] f32, transposed into Bs[n][k]
#pragma unroll
        for (int c = 0; c < 4; ++c) {
            int i = t + c * 256;
            int kr = i >> 4;
            int n4 = (i & 15) << 2;
            const float* sp = cls_w + (size_t)(k0 + kr) * CC + bn + n4;
            float4 v = {0.f, 0.f, 0.f, 0.f};
            if (bn + n4 + 3 < CC) {
                v = *(const float4*)sp;
            } else {
                if (bn + n4 + 0 < CC) v.x = sp[0];
                if (bn + n4 + 1 < CC) v.y = sp[1];
                if (bn + n4 + 2 < CC) v.z = sp[2];
                if (bn + n4 + 3 < CC) v.w = sp[3];
            }
            Bs[n4 + 0][kr] = (short)f2bf(v.x);
            Bs[n4 + 1][kr] = (short)f2bf(v.y);
            Bs[n4 + 2][kr] = (short)f2bf(v.z);
            Bs[n4 + 3][kr] = (short)f2bf(v.w);
        }
        __syncthreads();
#pragma unroll
        for (int ks = 0; ks < 2; ++ks) {
            int kk = ks * 32 + ((lane >> 4) << 3);
            int ar = lane & 15;
            bf16x8 a0 = *(const bf16x8*)&As[wm * 32 + ar][kk];
            bf16x8 a1 = *(const bf16x8*)&As[wm * 32 + 16 + ar][kk];
            bf16x8 b0 = *(const bf16x8*)&Bs[wn * 32 + ar][kk];
            bf16x8 b1 = *(const bf16x8*)&Bs[wn * 32 + 16 + ar][kk];
            acc[0][0] = __builtin_amdgcn_mfma_f32_16x16x32_bf16(a0, b0, acc[0][0], 0, 0, 0);
            acc[0][1] = __builtin_amdgcn_mfma_f32_16x16x32_bf16(a0, b1, acc[0][1], 0, 0, 0);
            acc[1][0] = __builtin_amdgcn_mfma_f32_16x16x32_bf16(a1, b0, acc[1][0], 0, 0, 0);
            acc[1][1] = __builtin_amdgcn_mfma_f32_16x16x32_bf16(a1, b1, acc[1][1], 0, 0, 0);
        }
        __syncthreads();
    }
    // transposed store: Mt[n][m] (bf16)
#pragma unroll
    for (int fm = 0; fm < 2; ++fm)
#pragma unroll
        for (int fn = 0; fn < 2; ++fn) {
            int gm0 = bm + wm * 32 + fm * 16 + ((lane >> 4) << 2);
            int gn = bn + wn * 32 + fn * 16 + (lane & 15);
            ushort4 o;
            o.x = f2bf(acc[fm][fn][0]); o.y = f2bf(acc[fm][fn][1]);
            o.z = f2bf(acc[fm][fn][2]); o.w = f2bf(acc[fm][fn][3]);
            *(ushort4*)(Mt + (size_t)gn * K2 + gm0) = o;
        }
}

// ---------------------------------------------------------------------------
// Fused node-reduce + GEMM2: part[z][2048][256] partial of
//   out = p @ Mt[:, 0:2048]^T + q @ Mt[:, 2048:4096]^T
// where p[b,:] = sum_u s[b,u]*pf[b,u,:], q[b,:] = sum_u pf[b,u,:] computed
// on the fly during A-staging (pf read exactly once, no pq intermediate).
// grid (64, 4): 32 rows x 256 cols per block, 4 waves of 32x64, BK=64.
// ---------------------------------------------------------------------------
__global__ __launch_bounds__(256) void k_fused(const float* __restrict__ pf,
                                               const float* __restrict__ cdds,
                                               const unsigned short* __restrict__ Mt,
                                               float* __restrict__ part)
{
    __shared__ short Asp[32][68];
    __shared__ short Asq[32][68];
    __shared__ short Bsp[256][68];
    __shared__ short Bsq[256][68];
    const int t = threadIdx.x;
    const int lane = t & 63;
    const int wid = t >> 6;
    const int bm = blockIdx.x * 32;          // batch rows
    const int z = blockIdx.y;
    const int kbase = z * (DD / ZSPLIT);     // 512-wide slice of DD

    // node weights for this thread's two staging rows
    const int r0 = t >> 4;                   // 0..15
    float sv0[NNODE], sv1[NNODE];
    compute_s(cdds, bm + r0, sv0);
    compute_s(cdds, bm + r0 + 16, sv1);

    f32x4 acc[2][4] = {};

    for (int k0 = kbase; k0 < kbase + DD / ZSPLIT; k0 += 64) {
        // ---- A: load pf rows, reduce 6 nodes -> p,q bf16 tiles
        const int k4 = (t & 15) << 2;
#pragma unroll
        for (int c = 0; c < 2; ++c) {
            int row = r0 + c * 16;
            const float* sva = c ? sv1 : sv0;
            const float* base = pf + ((size_t)(bm + row) * NNODE) * DD + k0 + k4;
            float4 p = {0.f, 0.f, 0.f, 0.f};
            float4 q = {0.f, 0.f, 0.f, 0.f};
#pragma unroll
            for (int u = 0; u < NNODE; ++u) {
                float4 a = *(const float4*)(base + (size_t)u * DD);
                p.x = fmaf(sva[u], a.x, p.x); p.y = fmaf(sva[u], a.y, p.y);
                p.z = fmaf(sva[u], a.z, p.z); p.w = fmaf(sva[u], a.w, p.w);
                q.x += a.x; q.y += a.y; q.z += a.z; q.w += a.w;
            }
            ushort4 pb, qb;
            pb.x = f2bf(p.x); pb.y = f2bf(p.y); pb.z = f2bf(p.z); pb.w = f2bf(p.w);
            qb.x = f2bf(q.x); qb.y = f2bf(q.y); qb.z = f2bf(q.z); qb.w = f2bf(q.w);
            *(ushort4*)&Asp[row][k4] = pb;
            *(ushort4*)&Asq[row][k4] = qb;
        }
        // ---- B: Mt rows (all 256 n), both k-halves
#pragma unroll
        for (int c = 0; c < 8; ++c) {
            int j = t + c * 256;
            int n = j >> 3;
            int k8 = (j & 7) << 3;
            *(uint4*)&Bsp[n][k8] = *(const uint4*)(Mt + (size_t)n * K2 + k0 + k8);
            *(uint4*)&Bsq[n][k8] = *(const uint4*)(Mt + (size_t)n * K2 + DD + k0 + k8);
        }
        __syncthreads();
#pragma unroll
        for (int ks = 0; ks < 2; ++ks) {
            int kk = ks * 32 + ((lane >> 4) << 3);
            int ar = lane & 15;
            bf16x8 ap0 = *(const bf16x8*)&Asp[ar][kk];
            bf16x8 ap1 = *(const bf16x8*)&Asp[ar + 16][kk];
            bf16x8 aq0 = *(const bf16x8*)&Asq[ar][kk];
            bf16x8 aq1 = *(const bf16x8*)&Asq[ar + 16][kk];
#pragma unroll
            for (int fn = 0; fn < 4; ++fn) {
                int nr = wid * 64 + fn * 16 + ar;
                bf16x8 bp = *(const bf16x8*)&Bsp[nr][kk];
                bf16x8 bq = *(const bf16x8*)&Bsq[nr][kk];
                acc[0][fn] = __builtin_amdgcn_mfma_f32_16x16x32_bf16(ap0, bp, acc[0][fn], 0, 0, 0);
                acc[1][fn] = __builtin_amdgcn_mfma_f32_16x16x32_bf16(ap1, bp, acc[1][fn], 0, 0, 0);
                acc[0][fn] = __builtin_amdgcn_mfma_f32_16x16x32_bf16(aq0, bq, acc[0][fn], 0, 0, 0);
                acc[1][fn] = __builtin_amdgcn_mfma_f32_16x16x32_bf16(aq1, bq, acc[1][fn], 0, 0, 0);
            }
        }
        __syncthreads();
    }
#pragma unroll
    for (int fm = 0; fm < 2; ++fm)
#pragma unroll
        for (int fn = 0; fn < 4; ++fn) {
            int gm0 = bm + fm * 16 + ((lane >> 4) << 2);
            int gn = wid * 64 + fn * 16 + (lane & 15);
#pragma unroll
            for (int r = 0; r < 4; ++r)
                part[((size_t)z * NB + gm0 + r) * NPAD + gn] = acc[fm][fn][r];
        }
}

// ---------------------------------------------------------------------------
// out[b,c] = (sum_z part[z][b][c]) / 6 + bvec[c]
// ---------------------------------------------------------------------------
__global__ __launch_bounds__(256) void k_combine(const float* __restrict__ part,
                                                 const float* __restrict__ bvec,
                                                 float* __restrict__ out)
{
    int idx = blockIdx.x * blockDim.x + threadIdx.x;
    if (idx >= NB * CC) return;
    int b = idx / CC;
    int c = idx - b * CC;
    float s = 0.f;
#pragma unroll
    for (int z = 0; z < ZSPLIT; ++z)
        s += part[((size_t)z * NB + b) * NPAD + c];
    out[idx] = s * (1.f / 6.f) + bvec[c];
}

// ---------------------------------------------------------------------------
extern "C" void kernel_launch(void* const* d_in, const int* in_sizes, int n_in,
                              void* d_out, int out_size, void* d_ws, size_t ws_size,
                              hipStream_t stream)
{
    const float* part_feats = (const float*)d_in[0];
    const float* cdds = (const float*)d_in[1];
    const float* fc_w = (const float*)d_in[2];   // (4096, 1024)
    const float* fc_b = (const float*)d_in[3];   // (1024,)
    const float* cls_w = (const float*)d_in[4];  // (1024, 200)
    const float* cls_b = (const float*)d_in[5];  // (200,)
    float* out = (float*)d_out;                  // (2048, 200)

    char* ws = (char*)d_ws;
    size_t off = 0;
    unsigned short* Mt = (unsigned short*)(ws + off); off += (size_t)NPAD * K2 * 2;          // 2.1 MB
    float* part = (float*)(ws + off);                 off += (size_t)ZSPLIT * NB * NPAD * 4; // 8.4 MB
    float* bvec = (float*)(ws + off);                 off += 256 * 4;

    // 1. Mt = (fc_w @ cls_w)^T bf16 (+ bvec in extra blocks)
    k_gemm1<<<dim3(256 + 25), dim3(256), 0, stream>>>(fc_w, cls_w, fc_b, cls_b, Mt, bvec);
    // 2. fused node-reduction + GEMM (part_feats read exactly once)
    k_fused<<<dim3(NB / 32, ZSPLIT), dim3(256), 0, stream>>>(part_feats, cdds, Mt, part);
    // 3. combine + scale + bias
    k_combine<<<dim3((NB * CC + 255) / 256), dim3(256), 0, stream>>>(part, bvec, out);
}

// Round 5
// 91.721 us; speedup vs baseline: 1.4047x; 1.4047x over previous
//
#include <hip/hip_runtime.h>
#include <math.h>

namespace {
constexpr int NB = 2048;      // batch
constexpr int NNODE = 6;      // nodes
constexpr int DD = 2048;      // feature dim
constexpr int HH = 1024;      // hidden
constexpr int CC = 200;       // classes
constexpr int K2 = 2 * DD;    // 4096 (concat dim)
constexpr int NPAD = 256;     // padded class dim
constexpr int ZS2 = 16;       // split-K for gemm2 (K per z = 256)
constexpr float ALPHA_C = 0.015f;
constexpr float SCALE_C = 24.0f;

constexpr int PQ_BLOCKS = NB * 2;                    // 4096
constexpr int G1_BLOCKS = (K2 / 64) * (NPAD / 64);   // 256
constexpr int BV_BLOCKS = 25;
}

typedef __attribute__((ext_vector_type(8))) short bf16x8;
typedef __attribute__((ext_vector_type(4))) float f32x4;

static __device__ __forceinline__ unsigned short f2bf(float x) {
    union { float f; unsigned int u; } v; v.f = x;
    unsigned int r = v.u + 0x7FFFu + ((v.u >> 16) & 1u);  // RNE
    return (unsigned short)(r >> 16);
}

// node weights s[u] for batch b
static __device__ __forceinline__ void compute_s(const float* __restrict__ cdds,
                                                 int b, float* sv) {
    const float* cd = cdds + (size_t)b * NNODE * 6;
    float cx[NNODE], cy[NNODE];
#pragma unroll
    for (int u = 0; u < NNODE; ++u) {
        cy[u] = (cd[u * 6 + 1] + cd[u * 6 + 3]) * 0.5f;
        cx[u] = (cd[u * 6 + 2] + cd[u * 6 + 4]) * 0.5f;
    }
    float w0[NNODE][NNODE];
    float sum = 0.f;
#pragma unroll
    for (int u = 0; u < NNODE; ++u)
#pragma unroll
        for (int v = 0; v < NNODE; ++v) {
            if (v == u) { w0[u][v] = 0.f; continue; }
            float dx = cx[u] - cx[v];
            float dy = cy[u] - cy[v];
            float w = expf(-ALPHA_C * sqrtf(dx * dx + dy * dy));
            w0[u][v] = w;
            sum += w;
        }
    float mean = sum * (1.f / 30.f);
#pragma unroll
    for (int u = 0; u < NNODE; ++u) {
        float acc = 0.f;
#pragma unroll
        for (int v = 0; v < NNODE; ++v) {
            float tt = w0[u][v] - mean;
            if (v != u && tt > 0.f) acc += tt;
        }
        sv[u] = SCALE_C * acc * 0.2f;   // /(N-1)
    }
}

// ---------------------------------------------------------------------------
// k_front: three independent jobs in one launch (co-scheduled across CUs):
//  blocks [0, 4096):       pq[b][0:D]=sum_u s*pf, pq[b][D:2D]=sum_u pf  (bf16)
//  blocks [4096, 4352):    Mt[256][4096] = (fc_w @ cls_w)^T  bf16 MFMA
//  blocks [4352, 4377):    bvec[c] = fc_b @ cls_w + cls_b
// ---------------------------------------------------------------------------
__global__ __launch_bounds__(256) void k_front(const float* __restrict__ pf,
                                               const float* __restrict__ cdds,
                                               const float* __restrict__ fc_w,
                                               const float* __restrict__ cls_w,
                                               const float* __restrict__ fc_b,
                                               const float* __restrict__ cls_b,
                                               unsigned short* __restrict__ pq,
                                               unsigned short* __restrict__ Mt,
                                               float* __restrict__ bvec)
{
    __shared__ short As[64][68];
    __shared__ short Bs[64][68];
    __shared__ float red[256];
    const int bx = blockIdx.x;
    const int t = threadIdx.x;

    if (bx < PQ_BLOCKS) {
        // ---------------- pq streaming ----------------
        int b = bx >> 1;
        int d = ((bx & 1) << 10) + (t << 2);
        float sv[NNODE];
        compute_s(cdds, b, sv);
        const float* base = pf + (size_t)b * NNODE * DD + d;
        float4 p = {0.f, 0.f, 0.f, 0.f};
        float4 q = {0.f, 0.f, 0.f, 0.f};
#pragma unroll
        for (int u = 0; u < NNODE; ++u) {
            float4 a = *(const float4*)(base + (size_t)u * DD);
            p.x = fmaf(sv[u], a.x, p.x); p.y = fmaf(sv[u], a.y, p.y);
            p.z = fmaf(sv[u], a.z, p.z); p.w = fmaf(sv[u], a.w, p.w);
            q.x += a.x; q.y += a.y; q.z += a.z; q.w += a.w;
        }
        unsigned short* o = pq + (size_t)b * K2;
        ushort4 pb, qb;
        pb.x = f2bf(p.x); pb.y = f2bf(p.y); pb.z = f2bf(p.z); pb.w = f2bf(p.w);
        qb.x = f2bf(q.x); qb.y = f2bf(q.y); qb.z = f2bf(q.z); qb.w = f2bf(q.w);
        *(ushort4*)(o + d) = pb;
        *(ushort4*)(o + DD + d) = qb;
        return;
    }

    if (bx >= PQ_BLOCKS + G1_BLOCKS) {
        // ---------------- bvec ----------------
        const int bb = bx - (PQ_BLOCKS + G1_BLOCKS);  // 0..24
        int c8 = t & 7;
        int hs = t >> 3;
        int c = bb * 8 + c8;              // < 200
        float acc = 0.f;
        for (int h = hs; h < HH; h += 32)
            acc += fc_b[h] * cls_w[(size_t)h * CC + c];
        red[t] = acc;
        __syncthreads();
        for (int s = 128; s >= 8; s >>= 1) {
            if (t < s) red[t] += red[t + s];
            __syncthreads();
        }
        if (t < 8) bvec[c] = red[t] + cls_b[c];
        return;
    }

    // ---------------- gemm1: Mt = (fc_w @ cls_w)^T ----------------
    const int bx2 = bx - PQ_BLOCKS;
    const int lane = t & 63;
    const int wid = t >> 6;
    const int wm = wid >> 1, wn = wid & 1;
    const int bm = (bx2 >> 2) * 64;       // over concat dim (4096)
    const int bn = (bx2 & 3) * 64;        // over class dim (256)

    f32x4 acc[2][2] = {};

    for (int k0 = 0; k0 < HH; k0 += 64) {
        // A tile 64x64: fc_w f32 -> bf16 (coalesced float4)
#pragma unroll
        for (int c = 0; c < 4; ++c) {
            int i = t + c * 256;
            int row = i >> 4;
            int k4 = (i & 15) << 2;
            float4 v = *(const float4*)(fc_w + (size_t)(bm + row) * HH + k0 + k4);
            ushort4 o;
            o.x = f2bf(v.x); o.y = f2bf(v.y); o.z = f2bf(v.z); o.w = f2bf(v.w);
            *(ushort4*)&As[row][k4] = o;
        }
        // B tile: cls_w[k][n] f32, transposed into Bs[n][k]
#pragma unroll
        for (int c = 0; c < 4; ++c) {
            int i = t + c * 256;
            int kr = i >> 4;
            int n4 = (i & 15) << 2;
            const float* sp = cls_w + (size_t)(k0 + kr) * CC + bn + n4;
            float4 v = {0.f, 0.f, 0.f, 0.f};
            if (bn + n4 + 3 < CC) {
                v = *(const float4*)sp;
            } else {
                if (bn + n4 + 0 < CC) v.x = sp[0];
                if (bn + n4 + 1 < CC) v.y = sp[1];
                if (bn + n4 + 2 < CC) v.z = sp[2];
                if (bn + n4 + 3 < CC) v.w = sp[3];
            }
            Bs[n4 + 0][kr] = (short)f2bf(v.x);
            Bs[n4 + 1][kr] = (short)f2bf(v.y);
            Bs[n4 + 2][kr] = (short)f2bf(v.z);
            Bs[n4 + 3][kr] = (short)f2bf(v.w);
        }
        __syncthreads();
#pragma unroll
        for (int ks = 0; ks < 2; ++ks) {
            int kk = ks * 32 + ((lane >> 4) << 3);
            int ar = lane & 15;
            bf16x8 a0 = *(const bf16x8*)&As[wm * 32 + ar][kk];
            bf16x8 a1 = *(const bf16x8*)&As[wm * 32 + 16 + ar][kk];
            bf16x8 b0 = *(const bf16x8*)&Bs[wn * 32 + ar][kk];
            bf16x8 b1 = *(const bf16x8*)&Bs[wn * 32 + 16 + ar][kk];
            acc[0][0] = __builtin_amdgcn_mfma_f32_16x16x32_bf16(a0, b0, acc[0][0], 0, 0, 0);
            acc[0][1] = __builtin_amdgcn_mfma_f32_16x16x32_bf16(a0, b1, acc[0][1], 0, 0, 0);
            acc[1][0] = __builtin_amdgcn_mfma_f32_16x16x32_bf16(a1, b0, acc[1][0], 0, 0, 0);
            acc[1][1] = __builtin_amdgcn_mfma_f32_16x16x32_bf16(a1, b1, acc[1][1], 0, 0, 0);
        }
        __syncthreads();
    }
    // transposed store: Mt[n][m] (rows m contiguous -> ushort4)
#pragma unroll
    for (int fm = 0; fm < 2; ++fm)
#pragma unroll
        for (int fn = 0; fn < 2; ++fn) {
            int gm0 = bm + wm * 32 + fm * 16 + ((lane >> 4) << 2);
            int gn = bn + wn * 32 + fn * 16 + (lane & 15);
            ushort4 o;
            o.x = f2bf(acc[fm][fn][0]); o.y = f2bf(acc[fm][fn][1]);
            o.z = f2bf(acc[fm][fn][2]); o.w = f2bf(acc[fm][fn][3]);
            *(ushort4*)(Mt + (size_t)gn * K2 + gm0) = o;
        }
}

// ---------------------------------------------------------------------------
// GEMM2: part[z][2048][256] = pq @ Mt^T partial (bf16 MFMA, split-K=16)
// grid (32, 16) = 512 blocks = 2/CU. Tile 64 x 256 (pq read exactly once),
// K per z = 256 (4 iters of 64). 4 waves: 32 rows x 128 cols, acc[2][8].
// ---------------------------------------------------------------------------
__global__ __launch_bounds__(256) void k_gemm2(const unsigned short* __restrict__ A,
                                               const unsigned short* __restrict__ Bt,
                                               float* __restrict__ part)
{
    __shared__ short As[64][72];    // 9.2 KB
    __shared__ short Bs[256][72];   // 36.9 KB
    const int t = threadIdx.x;
    const int lane = t & 63;
    const int wid = t >> 6;
    const int wr = wid >> 1, wc = wid & 1;
    const int bm = blockIdx.x * 64;
    const int z = blockIdx.y;
    const int kbase = z * (K2 / ZS2);   // 256 per z

    f32x4 acc[2][8] = {};

    for (int k0 = kbase; k0 < kbase + K2 / ZS2; k0 += 64) {
        // A tile 64x64 bf16
#pragma unroll
        for (int c = 0; c < 2; ++c) {
            int i = t + c * 256;
            int row = i >> 3;
            int k8 = (i & 7) << 3;
            *(uint4*)&As[row][k8] =
                *(const uint4*)(A + (size_t)(bm + row) * K2 + k0 + k8);
        }
        // B tile 256x64 bf16 (all classes)
#pragma unroll
        for (int c = 0; c < 8; ++c) {
            int i = t + c * 256;
            int n = i >> 3;
            int k8 = (i & 7) << 3;
            *(uint4*)&Bs[n][k8] =
                *(const uint4*)(Bt + (size_t)n * K2 + k0 + k8);
        }
        __syncthreads();
#pragma unroll
        for (int ks = 0; ks < 2; ++ks) {
            int kk = ks * 32 + ((lane >> 4) << 3);
            int ar = lane & 15;
            bf16x8 a0 = *(const bf16x8*)&As[wr * 32 + ar][kk];
            bf16x8 a1 = *(const bf16x8*)&As[wr * 32 + 16 + ar][kk];
#pragma unroll
            for (int fn = 0; fn < 8; ++fn) {
                bf16x8 b = *(const bf16x8*)&Bs[wc * 128 + fn * 16 + ar][kk];
                acc[0][fn] = __builtin_amdgcn_mfma_f32_16x16x32_bf16(a0, b, acc[0][fn], 0, 0, 0);
                acc[1][fn] = __builtin_amdgcn_mfma_f32_16x16x32_bf16(a1, b, acc[1][fn], 0, 0, 0);
            }
        }
        __syncthreads();
    }
#pragma unroll
    for (int fm = 0; fm < 2; ++fm)
#pragma unroll
        for (int fn = 0; fn < 8; ++fn) {
            int gm0 = bm + wr * 32 + fm * 16 + ((lane >> 4) << 2);
            int gn = wc * 128 + fn * 16 + (lane & 15);
#pragma unroll
            for (int r = 0; r < 4; ++r)
                part[((size_t)z * NB + gm0 + r) * NPAD + gn] = acc[fm][fn][r];
        }
}

// ---------------------------------------------------------------------------
// out[b,c] = (sum_z part[z][b][c]) / 6 + bvec[c]
// ---------------------------------------------------------------------------
__global__ __launch_bounds__(256) void k_combine(const float* __restrict__ part,
                                                 const float* __restrict__ bvec,
                                                 float* __restrict__ out)
{
    int idx = blockIdx.x * blockDim.x + threadIdx.x;
    if (idx >= NB * CC) return;
    int b = idx / CC;
    int c = idx - b * CC;
    float s = 0.f;
#pragma unroll
    for (int z = 0; z < ZS2; ++z)
        s += part[((size_t)z * NB + b) * NPAD + c];
    out[idx] = s * (1.f / 6.f) + bvec[c];
}

// ---------------------------------------------------------------------------
extern "C" void kernel_launch(void* const* d_in, const int* in_sizes, int n_in,
                              void* d_out, int out_size, void* d_ws, size_t ws_size,
                              hipStream_t stream)
{
    const float* part_feats = (const float*)d_in[0];
    const float* cdds = (const float*)d_in[1];
    const float* fc_w = (const float*)d_in[2];   // (4096, 1024)
    const float* fc_b = (const float*)d_in[3];   // (1024,)
    const float* cls_w = (const float*)d_in[4];  // (1024, 200)
    const float* cls_b = (const float*)d_in[5];  // (200,)
    float* out = (float*)d_out;                  // (2048, 200)

    char* ws = (char*)d_ws;
    size_t off = 0;
    unsigned short* pq = (unsigned short*)(ws + off); off += (size_t)NB * K2 * 2;        // 16.8 MB
    unsigned short* Mt = (unsigned short*)(ws + off); off += (size_t)NPAD * K2 * 2;      // 2.1 MB
    float* part = (float*)(ws + off);                 off += (size_t)ZS2 * NB * NPAD * 4;// 33.6 MB
    float* bvec = (float*)(ws + off);                 off += 256 * 4;

    // 1. pq streaming + gemm1 (Mt) + bvec, co-scheduled in one launch
    k_front<<<dim3(PQ_BLOCKS + G1_BLOCKS + BV_BLOCKS), dim3(256), 0, stream>>>(
        part_feats, cdds, fc_w, cls_w, fc_b, cls_b, pq, Mt, bvec);
    // 2. pq @ Mt^T partials, split-K=16
    k_gemm2<<<dim3(NB / 64, ZS2), dim3(256), 0, stream>>>(pq, Mt, part);
    // 3. combine + scale + bias
    k_combine<<<dim3((NB * CC + 255) / 256), dim3(256), 0, stream>>>(part, bvec, out);
}

// Round 6
// 76.794 us; speedup vs baseline: 1.6777x; 1.1944x over previous
//
#include <hip/hip_runtime.h>
#include <math.h>

namespace {
constexpr int NB = 2048;      // batch
constexpr int NNODE = 6;      // nodes
constexpr int DD = 2048;      // feature dim
constexpr int HH = 1024;      // hidden
constexpr int CC = 200;       // classes
constexpr int K2 = 2 * DD;    // 4096 (concat dim)
constexpr int NPAD = 256;     // padded class dim
constexpr int ZS2 = 16;       // split-K for gemm2 (K per z = 256)
constexpr float ALPHA_C = 0.015f;
constexpr float SCALE_C = 24.0f;

constexpr int G1_BLOCKS = (K2 / 64) * (NPAD / 64);   // 256
constexpr int BV_BLOCKS = 25;
constexpr int PQ_BASE = G1_BLOCKS + BV_BLOCKS;       // 281
}

typedef __attribute__((ext_vector_type(8))) short bf16x8;
typedef __attribute__((ext_vector_type(4))) float f32x4;

static __device__ __forceinline__ unsigned short f2bf(float x) {
    union { float f; unsigned int u; } v; v.f = x;
    unsigned int r = v.u + 0x7FFFu + ((v.u >> 16) & 1u);  // RNE
    return (unsigned short)(r >> 16);
}

static __device__ __forceinline__ unsigned pack2(float a, float b) {
    return (unsigned)f2bf(a) | ((unsigned)f2bf(b) << 16);
}

// ---------------------------------------------------------------------------
// Wave-parallel node weights: lane (u*8+v) computes one exp+sqrt; butterfly
// reduce for mean; 8-lane-group reduce for row sums; broadcast s[0..5].
// ---------------------------------------------------------------------------
static __device__ __forceinline__ void compute_s_wave(const float* __restrict__ cdds,
                                                      int b, float sv[NNODE]) {
    const int lane = threadIdx.x & 63;
    const int u = lane >> 3;      // 0..7
    const int v = lane & 7;       // 0..7
    const float* cd = cdds + (size_t)b * 36;
    float w = 0.f;
    const bool valid = (u < 6) & (v < 6) & (u != v);
    if (u < 6 && v < 6 && u != v) {
        float cyu = (cd[u * 6 + 1] + cd[u * 6 + 3]) * 0.5f;
        float cxu = (cd[u * 6 + 2] + cd[u * 6 + 4]) * 0.5f;
        float cyv = (cd[v * 6 + 1] + cd[v * 6 + 3]) * 0.5f;
        float cxv = (cd[v * 6 + 2] + cd[v * 6 + 4]) * 0.5f;
        float dx = cxu - cxv, dy = cyu - cyv;
        w = expf(-ALPHA_C * sqrtf(dx * dx + dy * dy));
    }
    // full-wave sum of w  -> mean
    float s = w;
#pragma unroll
    for (int m = 32; m >= 1; m >>= 1) s += __shfl_xor(s, m);
    float mean = s * (1.f / 30.f);
    // thresholded, row-reduced within each 8-lane group
    float tt = valid ? fmaxf(w - mean, 0.f) : 0.f;
    tt += __shfl_xor(tt, 1);
    tt += __shfl_xor(tt, 2);
    tt += __shfl_xor(tt, 4);
    float su = SCALE_C * tt * 0.2f;   // s[u] for this lane's row u
#pragma unroll
    for (int uu = 0; uu < NNODE; ++uu) sv[uu] = __shfl(su, uu * 8);
}

// ---------------------------------------------------------------------------
// k_front: three independent jobs, gemm1/bvec blocks FIRST so they get
// resident immediately and co-schedule under the pq stream.
//  blocks [0,256):    Mt[256][4096] = (fc_w @ cls_w)^T  bf16 MFMA
//  blocks [256,281):  bvec[c] = fc_b @ cls_w + cls_b
//  blocks [281,2329): pq[b][0:D]=sum_u s*pf, pq[b][D:2D]=sum_u pf  (bf16)
// ---------------------------------------------------------------------------
__global__ __launch_bounds__(256) void k_front(const float* __restrict__ pf,
                                               const float* __restrict__ cdds,
                                               const float* __restrict__ fc_w,
                                               const float* __restrict__ cls_w,
                                               const float* __restrict__ fc_b,
                                               const float* __restrict__ cls_b,
                                               unsigned short* __restrict__ pq,
                                               unsigned short* __restrict__ Mt,
                                               float* __restrict__ bvec)
{
    __shared__ short As[64][68];
    __shared__ short Bs[64][68];
    __shared__ float red[256];
    const int bx = blockIdx.x;
    const int t = threadIdx.x;

    if (bx >= PQ_BASE) {
        // ---------------- pq streaming: one block per batch ----------------
        const int b = bx - PQ_BASE;
        float sv[NNODE];
        compute_s_wave(cdds, b, sv);
        const int d = t << 3;   // 8 floats per thread
        const float* base = pf + (size_t)b * NNODE * DD + d;
        float4 p0 = {0, 0, 0, 0}, p1 = {0, 0, 0, 0};
        float4 q0 = {0, 0, 0, 0}, q1 = {0, 0, 0, 0};
#pragma unroll
        for (int u = 0; u < NNODE; ++u) {
            float4 a0 = *(const float4*)(base + (size_t)u * DD);
            float4 a1 = *(const float4*)(base + (size_t)u * DD + 4);
            float s = sv[u];
            p0.x = fmaf(s, a0.x, p0.x); p0.y = fmaf(s, a0.y, p0.y);
            p0.z = fmaf(s, a0.z, p0.z); p0.w = fmaf(s, a0.w, p0.w);
            p1.x = fmaf(s, a1.x, p1.x); p1.y = fmaf(s, a1.y, p1.y);
            p1.z = fmaf(s, a1.z, p1.z); p1.w = fmaf(s, a1.w, p1.w);
            q0.x += a0.x; q0.y += a0.y; q0.z += a0.z; q0.w += a0.w;
            q1.x += a1.x; q1.y += a1.y; q1.z += a1.z; q1.w += a1.w;
        }
        unsigned short* o = pq + (size_t)b * K2;
        uint4 po, qo;
        po.x = pack2(p0.x, p0.y); po.y = pack2(p0.z, p0.w);
        po.z = pack2(p1.x, p1.y); po.w = pack2(p1.z, p1.w);
        qo.x = pack2(q0.x, q0.y); qo.y = pack2(q0.z, q0.w);
        qo.z = pack2(q1.x, q1.y); qo.w = pack2(q1.z, q1.w);
        *(uint4*)(o + d) = po;
        *(uint4*)(o + DD + d) = qo;
        return;
    }

    if (bx >= G1_BLOCKS) {
        // ---------------- bvec ----------------
        const int bb = bx - G1_BLOCKS;    // 0..24
        int c8 = t & 7;
        int hs = t >> 3;
        int c = bb * 8 + c8;              // < 200
        float acc = 0.f;
        for (int h = hs; h < HH; h += 32)
            acc += fc_b[h] * cls_w[(size_t)h * CC + c];
        red[t] = acc;
        __syncthreads();
        for (int s = 128; s >= 8; s >>= 1) {
            if (t < s) red[t] += red[t + s];
            __syncthreads();
        }
        if (t < 8) bvec[c] = red[t] + cls_b[c];
        return;
    }

    // ---------------- gemm1: Mt = (fc_w @ cls_w)^T ----------------
    const int lane = t & 63;
    const int wid = t >> 6;
    const int wm = wid >> 1, wn = wid & 1;
    const int bm = (bx >> 2) * 64;        // over concat dim (4096)
    const int bn = (bx & 3) * 64;         // over class dim (256)

    f32x4 acc[2][2] = {};

    for (int k0 = 0; k0 < HH; k0 += 64) {
        // A tile 64x64: fc_w f32 -> bf16 (coalesced float4)
#pragma unroll
        for (int c = 0; c < 4; ++c) {
            int i = t + c * 256;
            int row = i >> 4;
            int k4 = (i & 15) << 2;
            float4 v = *(const float4*)(fc_w + (size_t)(bm + row) * HH + k0 + k4);
            ushort4 o;
            o.x = f2bf(v.x); o.y = f2bf(v.y); o.z = f2bf(v.z); o.w = f2bf(v.w);
            *(ushort4*)&As[row][k4] = o;
        }
        // B tile: cls_w[k][n] f32, transposed into Bs[n][k]
#pragma unroll
        for (int c = 0; c < 4; ++c) {
            int i = t + c * 256;
            int kr = i >> 4;
            int n4 = (i & 15) << 2;
            const float* sp = cls_w + (size_t)(k0 + kr) * CC + bn + n4;
            float4 v = {0.f, 0.f, 0.f, 0.f};
            if (bn + n4 + 3 < CC) {
                v = *(const float4*)sp;
            } else {
                if (bn + n4 + 0 < CC) v.x = sp[0];
                if (bn + n4 + 1 < CC) v.y = sp[1];
                if (bn + n4 + 2 < CC) v.z = sp[2];
                if (bn + n4 + 3 < CC) v.w = sp[3];
            }
            Bs[n4 + 0][kr] = (short)f2bf(v.x);
            Bs[n4 + 1][kr] = (short)f2bf(v.y);
            Bs[n4 + 2][kr] = (short)f2bf(v.z);
            Bs[n4 + 3][kr] = (short)f2bf(v.w);
        }
        __syncthreads();
#pragma unroll
        for (int ks = 0; ks < 2; ++ks) {
            int kk = ks * 32 + ((lane >> 4) << 3);
            int ar = lane & 15;
            bf16x8 a0 = *(const bf16x8*)&As[wm * 32 + ar][kk];
            bf16x8 a1 = *(const bf16x8*)&As[wm * 32 + 16 + ar][kk];
            bf16x8 b0 = *(const bf16x8*)&Bs[wn * 32 + ar][kk];
            bf16x8 b1 = *(const bf16x8*)&Bs[wn * 32 + 16 + ar][kk];
            acc[0][0] = __builtin_amdgcn_mfma_f32_16x16x32_bf16(a0, b0, acc[0][0], 0, 0, 0);
            acc[0][1] = __builtin_amdgcn_mfma_f32_16x16x32_bf16(a0, b1, acc[0][1], 0, 0, 0);
            acc[1][0] = __builtin_amdgcn_mfma_f32_16x16x32_bf16(a1, b0, acc[1][0], 0, 0, 0);
            acc[1][1] = __builtin_amdgcn_mfma_f32_16x16x32_bf16(a1, b1, acc[1][1], 0, 0, 0);
        }
        __syncthreads();
    }
    // transposed store: Mt[n][m]
#pragma unroll
    for (int fm = 0; fm < 2; ++fm)
#pragma unroll
        for (int fn = 0; fn < 2; ++fn) {
            int gm0 = bm + wm * 32 + fm * 16 + ((lane >> 4) << 2);
            int gn = bn + wn * 32 + fn * 16 + (lane & 15);
            ushort4 o;
            o.x = f2bf(acc[fm][fn][0]); o.y = f2bf(acc[fm][fn][1]);
            o.z = f2bf(acc[fm][fn][2]); o.w = f2bf(acc[fm][fn][3]);
            *(ushort4*)(Mt + (size_t)gn * K2 + gm0) = o;
        }
}

// ---------------------------------------------------------------------------
// GEMM2: part[z][2048][256] = pq @ Mt^T partial (bf16 MFMA, split-K=16)
// grid (32, 16) = 512 blocks = 2/CU. Tile 64 x 256, K per z = 256.
// ---------------------------------------------------------------------------
__global__ __launch_bounds__(256) void k_gemm2(const unsigned short* __restrict__ A,
                                               const unsigned short* __restrict__ Bt,
                                               float* __restrict__ part)
{
    __shared__ short As[64][72];    // 9.2 KB
    __shared__ short Bs[256][72];   // 36.9 KB
    const int t = threadIdx.x;
    const int lane = t & 63;
    const int wid = t >> 6;
    const int wr = wid >> 1, wc = wid & 1;
    const int bm = blockIdx.x * 64;
    const int z = blockIdx.y;
    const int kbase = z * (K2 / ZS2);   // 256 per z

    f32x4 acc[2][8] = {};

    for (int k0 = kbase; k0 < kbase + K2 / ZS2; k0 += 64) {
#pragma unroll
        for (int c = 0; c < 2; ++c) {
            int i = t + c * 256;
            int row = i >> 3;
            int k8 = (i & 7) << 3;
            *(uint4*)&As[row][k8] =
                *(const uint4*)(A + (size_t)(bm + row) * K2 + k0 + k8);
        }
#pragma unroll
        for (int c = 0; c < 8; ++c) {
            int i = t + c * 256;
            int n = i >> 3;
            int k8 = (i & 7) << 3;
            *(uint4*)&Bs[n][k8] =
                *(const uint4*)(Bt + (size_t)n * K2 + k0 + k8);
        }
        __syncthreads();
#pragma unroll
        for (int ks = 0; ks < 2; ++ks) {
            int kk = ks * 32 + ((lane >> 4) << 3);
            int ar = lane & 15;
            bf16x8 a0 = *(const bf16x8*)&As[wr * 32 + ar][kk];
            bf16x8 a1 = *(const bf16x8*)&As[wr * 32 + 16 + ar][kk];
#pragma unroll
            for (int fn = 0; fn < 8; ++fn) {
                bf16x8 b = *(const bf16x8*)&Bs[wc * 128 + fn * 16 + ar][kk];
                acc[0][fn] = __builtin_amdgcn_mfma_f32_16x16x32_bf16(a0, b, acc[0][fn], 0, 0, 0);
                acc[1][fn] = __builtin_amdgcn_mfma_f32_16x16x32_bf16(a1, b, acc[1][fn], 0, 0, 0);
            }
        }
        __syncthreads();
    }
#pragma unroll
    for (int fm = 0; fm < 2; ++fm)
#pragma unroll
        for (int fn = 0; fn < 8; ++fn) {
            int gm0 = bm + wr * 32 + fm * 16 + ((lane >> 4) << 2);
            int gn = wc * 128 + fn * 16 + (lane & 15);
#pragma unroll
            for (int r = 0; r < 4; ++r)
                part[((size_t)z * NB + gm0 + r) * NPAD + gn] = acc[fm][fn][r];
        }
}

// ---------------------------------------------------------------------------
// out[b,c] = (sum_z part[z][b][c]) / 6 + bvec[c]
// ---------------------------------------------------------------------------
__global__ __launch_bounds__(256) void k_combine(const float* __restrict__ part,
                                                 const float* __restrict__ bvec,
                                                 float* __restrict__ out)
{
    int idx = blockIdx.x * blockDim.x + threadIdx.x;
    if (idx >= NB * CC) return;
    int b = idx / CC;
    int c = idx - b * CC;
    float s = 0.f;
#pragma unroll
    for (int z = 0; z < ZS2; ++z)
        s += part[((size_t)z * NB + b) * NPAD + c];
    out[idx] = s * (1.f / 6.f) + bvec[c];
}

// ---------------------------------------------------------------------------
extern "C" void kernel_launch(void* const* d_in, const int* in_sizes, int n_in,
                              void* d_out, int out_size, void* d_ws, size_t ws_size,
                              hipStream_t stream)
{
    const float* part_feats = (const float*)d_in[0];
    const float* cdds = (const float*)d_in[1];
    const float* fc_w = (const float*)d_in[2];   // (4096, 1024)
    const float* fc_b = (const float*)d_in[3];   // (1024,)
    const float* cls_w = (const float*)d_in[4];  // (1024, 200)
    const float* cls_b = (const float*)d_in[5];  // (200,)
    float* out = (float*)d_out;                  // (2048, 200)

    char* ws = (char*)d_ws;
    size_t off = 0;
    unsigned short* pq = (unsigned short*)(ws + off); off += (size_t)NB * K2 * 2;        // 16.8 MB
    unsigned short* Mt = (unsigned short*)(ws + off); off += (size_t)NPAD * K2 * 2;      // 2.1 MB
    float* part = (float*)(ws + off);                 off += (size_t)ZS2 * NB * NPAD * 4;// 33.6 MB
    float* bvec = (float*)(ws + off);                 off += 256 * 4;

    // 1. gemm1 (Mt) + bvec + pq streaming, co-scheduled in one launch
    k_front<<<dim3(PQ_BASE + NB), dim3(256), 0, stream>>>(
        part_feats, cdds, fc_w, cls_w, fc_b, cls_b, pq, Mt, bvec);
    // 2. pq @ Mt^T partials, split-K=16
    k_gemm2<<<dim3(NB / 64, ZS2), dim3(256), 0, stream>>>(pq, Mt, part);
    // 3. combine + scale + bias
    k_combine<<<dim3((NB * CC + 255) / 256), dim3(256), 0, stream>>>(part, bvec, out);
}